// Round 6
// baseline (28.112 us; speedup 1.0000x reference)
//
#include <hip/hip_runtime.h>

// NodeCycleFeatures: B=2048 graphs, N=64, A = E[...,1] symmetric 0/1, zero diag.
// ONE wave per batch (64-thread blocks, grid 2048). Zero cross-wave traffic,
// barriers are wave-local (free). Lane i owns row i; ALL 64 row masks are
// register-resident (rl/rh[64]), so phases 2/3 are pure register VALU.
// k2[i][k] = popcount(row_i & row_k) (<=62, exact); k2 row kept as 6 bit-planes
// -> k3[i][j] = sum_t 2^t popcount(plane_t & row_j). Integer partials (exact),
// converted to f32 at the end. Identity used: (A@d)[i] = sum_k k2[i][k].

constexpr int BATCH = 2048;
constexpr int NN = 64;

__global__ __launch_bounds__(64, 2) void node_cycle_kernel(
    const float4* __restrict__ E4,   // [B,N,N,2] floats viewed as float4
    const float* __restrict__ nmask, // [B,N]
    float* __restrict__ out)         // x: [B,N,3] then y: [B,4]
{
  const int b = blockIdx.x;
  const int lane = threadIdx.x;

  __shared__ uint2 rowsh[NN];
  __shared__ unsigned c3sh[NN];

  const float4* __restrict__ Eb = E4 + (size_t)b * (NN * NN / 2);

  // ---- Phase 1: build column masks (== rows; A symmetric) from coalesced
  // float4 loads. float4 #(t*64+lane) holds A-row (2t + (lane>=32)), cols
  // 2*(lane&31) and +1 in .y/.w. shfl_xor(32) merges the two row-parities.
  unsigned long long mAq = 0ull, mBq = 0ull;
  const int rbase = (lane >= 32) ? 1 : 0;
  #pragma unroll
  for (int t = 0; t < 32; ++t) {
    const float4 f = Eb[t * 64 + lane];
    const int bitpos = 2 * t + rbase;
    mAq |= (unsigned long long)(f.y > 0.5f) << bitpos;
    mBq |= (unsigned long long)(f.w > 0.5f) << bitpos;
  }
  mAq |= __shfl_xor(mAq, 32);
  mBq |= __shfl_xor(mBq, 32);
  if (lane < 32) {
    rowsh[2 * lane]     = make_uint2((unsigned)mAq, (unsigned)(mAq >> 32));
    rowsh[2 * lane + 1] = make_uint2((unsigned)mBq, (unsigned)(mBq >> 32));
  }
  __syncthreads();   // single-wave block: cheap wave-local barrier

  const unsigned mlo = rowsh[lane].x;
  const unsigned mhi = rowsh[lane].y;

  // ---- All 64 rows -> registers (static indices only; SROA to VGPRs) ----
  unsigned rl[NN], rh[NN];
  #pragma unroll
  for (int k = 0; k < NN; ++k) {
    const uint2 r = rowsh[k];
    rl[k] = r.x; rh[k] = r.y;
  }

  // ---- Phase 2: k2 row -> 6 bit-planes; integer partials ----
  unsigned plo[6] = {0u,0u,0u,0u,0u,0u};
  unsigned phi[6] = {0u,0u,0u,0u,0u,0u};
  unsigned diag4i = 0u, Adi = 0u, c3i = 0u, t3i = 0u;
  #pragma unroll
  for (int k = 0; k < NN; ++k) {
    const unsigned p = (unsigned)__popc(rl[k] & mlo) + (unsigned)__popc(rh[k] & mhi);
    if (k < 32) {
      #pragma unroll
      for (int t = 0; t < 6; ++t) plo[t] |= ((p >> t) & 1u) << k;
    } else {
      #pragma unroll
      for (int t = 0; t < 6; ++t) phi[t] |= ((p >> t) & 1u) << (k - 32);
    }
    diag4i += p * p;                                // diag(A^4)
    Adi += p;                                       // (A@d)[i] = row-sum of k2
    const unsigned bit = ((k < 32 ? (mlo >> k) : (mhi >> (k - 32))) & 1u);
    const unsigned selp = bit ? p : 0u;
    c3i += selp;                                    // diag(A^3)
    t3i += selp * p;                                // sum A*k2^2 (row part)
  }
  c3sh[lane] = c3i;
  __syncthreads();

  // ---- Phase 3: k3[lane][j] via bit-plane popcounts (pure registers) ----
  float t1f = 0.f;
  unsigned t8i = 0u, diag5i = 0u, Atrii = 0u;
  #pragma unroll
  for (int j = 0; j < NN; ++j) {
    const unsigned a = rl[j], bb = rh[j];
    unsigned s = (unsigned)__popc(plo[0] & a) + (unsigned)__popc(phi[0] & bb);
    s += ((unsigned)__popc(plo[1] & a) + (unsigned)__popc(phi[1] & bb)) << 1;
    s += ((unsigned)__popc(plo[2] & a) + (unsigned)__popc(phi[2] & bb)) << 2;
    s += ((unsigned)__popc(plo[3] & a) + (unsigned)__popc(phi[3] & bb)) << 3;
    s += ((unsigned)__popc(plo[4] & a) + (unsigned)__popc(phi[4] & bb)) << 4;
    s += ((unsigned)__popc(plo[5] & a) + (unsigned)__popc(phi[5] & bb)) << 5;
    const unsigned pj = (unsigned)__popc(a & mlo) + (unsigned)__popc(bb & mhi);
    const float sf = (float)s;
    t1f = fmaf(sf, sf, t1f);                        // -> trace(k6)
    t8i += s;                                       // -> sum(k3)
    diag5i += pj * s;                               // -> diag(A^5)
    const unsigned bit = ((j < 32 ? (mlo >> j) : (mhi >> (j - 32))) & 1u);
    Atrii += bit ? c3sh[j] : 0u;                    // -> (A@c3)[i]
  }

  // ---- Per-lane node quantities (exact int -> f32) ----
  const float di    = (float)(__popc(mlo) + __popc(mhi));
  const float c3f   = (float)c3i;
  const float diag4 = (float)diag4i;
  const float Ad    = (float)Adi;
  const float t3p   = (float)t3i;
  const float t8p   = (float)t8i;
  const float diag5 = (float)diag5i;
  const float Atri  = (float)Atrii;

  const float c4 = diag4 - di * (di - 1.f) - Ad;
  const float c5 = diag5 - 2.f * c3f * di - Atri + c3f;
  const float c6p = t1f
            - 3.f * (c3f * c3f)
            + 9.f * t3p
            - 6.f * (di * diag4)
            + 6.f * diag4
            - 4.f * c3f
            + 4.f * (di * di * di)
            + 3.f * t8p
            - 12.f * (di * di)
            + 4.f * di;

  // ---- Wave reduction of the four batch sums ----
  float sc3 = c3f, sc4 = c4, sc5 = c5, sc6 = c6p;
  #pragma unroll
  for (int off = 32; off > 0; off >>= 1) {
    sc3 += __shfl_xor(sc3, off);
    sc4 += __shfl_xor(sc4, off);
    sc5 += __shfl_xor(sc5, off);
    sc6 += __shfl_xor(sc6, off);
  }

  // ---- Outputs ----
  const float m = nmask[b * NN + lane];
  float* xo = out + ((size_t)b * NN + lane) * 3;
  xo[0] = fminf(c3f * 0.5f * m * 0.1f, 1.f);
  xo[1] = fminf(c4 * 0.5f * m * 0.1f, 1.f);
  xo[2] = fminf(c5 * 0.5f * m * 0.1f, 1.f);

  if (lane == 0) {
    float4 y;
    y.x = fminf(sc3 * (1.f / 6.f)  * 0.1f, 1.f);
    y.y = fminf(sc4 * (1.f / 8.f)  * 0.1f, 1.f);
    y.z = fminf(sc5 * (1.f / 10.f) * 0.1f, 1.f);
    y.w = fminf(sc6 * (1.f / 12.f) * 0.1f, 1.f);
    *reinterpret_cast<float4*>(out + (size_t)BATCH * NN * 3 + b * 4) = y;
  }
}

extern "C" void kernel_launch(void* const* d_in, const int* in_sizes, int n_in,
                              void* d_out, int out_size, void* d_ws, size_t ws_size,
                              hipStream_t stream) {
  const float4* E4 = reinterpret_cast<const float4*>(d_in[0]);
  const float* nmask = reinterpret_cast<const float*>(d_in[1]);
  float* out = reinterpret_cast<float*>(d_out);
  node_cycle_kernel<<<BATCH, NN, 0, stream>>>(E4, nmask, out);
}

// Round 7
// 26.627 us; speedup vs baseline: 1.0558x; 1.0558x over previous
//
#include <hip/hip_runtime.h>

// NodeCycleFeatures: B=2048 graphs, N=64, A = E[...,1] symmetric 0/1, zero diag.
// 4 waves per block-batch; 2 batches per block, software-pipelined (batch m+1's
// A values prefetched into registers during batch m's compute).
// Lane i owns row i as a 64-bit mask; wave w owns k/j-subrange [16w,16w+16).
// k2[i][k] = popcount(row_i & row_k), kept as 6 bit-planes ->
// k3[i][j] = sum_t 2^t popcount(plane_t & row_j). Integer-exact in fp32.
// 3 barriers/batch: S3 removed via redundant per-wave c3 merge (identical-value
// LDS writes are benign). (A@d)[i] = sum_k k2[i][k] folded into phase 2.

constexpr int BATCH = 2048;
constexpr int NN = 64;
constexpr int NB = 2;               // batches per block (pipelined)
constexpr int GRID = BATCH / NB;

union UF { unsigned u; float f; };

__global__ __launch_bounds__(256, 4) void node_cycle_kernel(
    const float* __restrict__ Ef,    // [B,N,N,2] floats; A = element .y
    const float* __restrict__ nmask, // [B,N]
    float* __restrict__ out)         // x: [B,N,3] then y: [B,4]
{
  const int tid = threadIdx.x;
  const int lane = tid & 63;
  const int w = tid >> 6;            // wave id 0..3
  const int k0 = w * 16;             // this wave's k/j subrange base
  const int b0 = blockIdx.x * NB;

  __shared__ uint4 jinfo[NN];                  // {row_lo, row_hi, c3_bits, -}
  __shared__ unsigned ppart[4][6][NN];         // partial bit-planes (16 bits)
  __shared__ float c3part[4][NN];
  __shared__ float accs[4][7][NN];             // per-wave float partials

  // ---- Prologue: prefetch batch b0's A values (.y floats only) ----
  float pref[16];
  #pragma unroll
  for (int q = 0; q < 16; ++q)
    pref[q] = Ef[(((size_t)b0 * (NN * NN)) + (k0 + q) * NN + lane) * 2 + 1];

  for (int m = 0; m < NB; ++m) {
    const int b = b0 + m;

    // ---- Phase 1: ballot row masks from prefetched registers ----
    #pragma unroll
    for (int q = 0; q < 16; ++q) {
      const int r = k0 + q;
      const unsigned long long msk = __ballot(pref[q] > 0.5f);
      if (lane == r) {
        jinfo[r].x = (unsigned)msk;
        jinfo[r].y = (unsigned)(msk >> 32);
      }
    }
    // Issue next batch's loads NOW; in flight across phases 2/3.
    if (m + 1 < NB) {
      #pragma unroll
      for (int q = 0; q < 16; ++q)
        pref[q] = Ef[(((size_t)(b + 1) * (NN * NN)) + (k0 + q) * NN + lane) * 2 + 1];
    }
    __syncthreads();                            // S1

    const unsigned mlo = jinfo[lane].x;         // lane i holds row i
    const unsigned mhi = jinfo[lane].y;
    const unsigned long long myrow = ((unsigned long long)mhi << 32) | mlo;
    const unsigned nb16 = (unsigned)(myrow >> k0) & 0xffffu; // bit q = A[lane][k0+q]

    // ---- Phase 2: k2[lane][k] (k in subrange); planes + diag4/c3/t3/Ad ----
    unsigned pp0=0,pp1=0,pp2=0,pp3=0,pp4=0,pp5=0;
    unsigned pk[4] = {0u,0u,0u,0u};
    float diag4 = 0.f, c3 = 0.f, t3p = 0.f, Ad = 0.f;
    #pragma unroll
    for (int q = 0; q < 16; ++q) {
      const uint4 ji = jinfo[k0 + q];           // uniform broadcast b128 (.xy used)
      const unsigned p = (unsigned)__popc(ji.x & mlo) + (unsigned)__popc(ji.y & mhi);
      pp0 |= ((p      ) & 1u) << q;
      pp1 |= ((p >> 1) & 1u) << q;
      pp2 |= ((p >> 2) & 1u) << q;
      pp3 |= ((p >> 3) & 1u) << q;
      pp4 |= ((p >> 4) & 1u) << q;
      pp5 |= ((p >> 5) & 1u) << q;
      pk[q >> 2] |= p << (8 * (q & 3));         // static index under unroll
      const float pf = (float)p;
      diag4 = fmaf(pf, pf, diag4);
      Ad += pf;                                 // (A@d)[i] = sum_k k2[i][k]
      const float selpf = ((nb16 >> q) & 1u) ? pf : 0.f;
      c3 += selpf;
      t3p = fmaf(selpf, pf, t3p);
    }
    ppart[w][0][lane]=pp0; ppart[w][1][lane]=pp1; ppart[w][2][lane]=pp2;
    ppart[w][3][lane]=pp3; ppart[w][4][lane]=pp4; ppart[w][5][lane]=pp5;
    c3part[w][lane] = c3;
    accs[w][0][lane] = diag4;
    accs[w][1][lane] = t3p;
    accs[w][2][lane] = Ad;
    __syncthreads();                            // S2

    // ---- Merge (redundant in every wave; no extra barrier needed) ----
    unsigned pl_lo[6], pl_hi[6];
    #pragma unroll
    for (int t = 0; t < 6; ++t) {
      pl_lo[t] = ppart[0][t][lane] | (ppart[1][t][lane] << 16);
      pl_hi[t] = ppart[2][t][lane] | (ppart[3][t][lane] << 16);
    }
    const float c3f = c3part[0][lane] + c3part[1][lane]
                    + c3part[2][lane] + c3part[3][lane];
    { UF u; u.f = c3f; jinfo[lane].z = u.u; }   // all waves write identical value

    // ---- Phase 3: k3[lane][j] via bit-plane popcounts ----
    float t1p=0.f, t8p=0.f, diag5=0.f, Atri=0.f;
    #pragma unroll
    for (int q = 0; q < 16; ++q) {
      const uint4 ji = jinfo[k0 + q];           // uniform broadcast b128
      unsigned s = (unsigned)__popc(pl_lo[0] & ji.x) + (unsigned)__popc(pl_hi[0] & ji.y);
      s += ((unsigned)__popc(pl_lo[1] & ji.x) + (unsigned)__popc(pl_hi[1] & ji.y)) << 1;
      s += ((unsigned)__popc(pl_lo[2] & ji.x) + (unsigned)__popc(pl_hi[2] & ji.y)) << 2;
      s += ((unsigned)__popc(pl_lo[3] & ji.x) + (unsigned)__popc(pl_hi[3] & ji.y)) << 3;
      s += ((unsigned)__popc(pl_lo[4] & ji.x) + (unsigned)__popc(pl_hi[4] & ji.y)) << 4;
      s += ((unsigned)__popc(pl_lo[5] & ji.x) + (unsigned)__popc(pl_hi[5] & ji.y)) << 5;
      const unsigned pj = (pk[q >> 2] >> (8 * (q & 3))) & 0xffu; // k2[lane][j]
      const float sf = (float)s;
      t1p = fmaf(sf, sf, t1p);                  // -> trace(k6)
      t8p += sf;                                // -> sum(k3)
      diag5 = fmaf((float)pj, sf, diag5);       // -> diag(A^5)
      UF cj; cj.u = ji.z;                       // c3(j)
      Atri += ((nb16 >> q) & 1u) ? cj.f : 0.f;  // -> (A@c3)[i]
    }
    accs[w][3][lane]=t1p; accs[w][4][lane]=t8p;
    accs[w][5][lane]=diag5; accs[w][6][lane]=Atri;
    __syncthreads();                            // S4

    // ---- Final: wave 0 merges partials, computes outputs ----
    // (w1-3 race ahead into next phase 1; they only write jinfo.x/.y,
    //  never read here. Next S1 re-orders everything.)
    if (w == 0) {
      float f[7];
      #pragma unroll
      for (int q2 = 0; q2 < 7; ++q2)
        f[q2] = accs[0][q2][lane] + accs[1][q2][lane]
              + accs[2][q2][lane] + accs[3][q2][lane];
      const float diag4F=f[0], t3F=f[1], AdF=f[2], t1F=f[3], t8F=f[4], d5F=f[5], AtF=f[6];
      const float di = (float)(__popc(mlo) + __popc(mhi));

      const float c4 = diag4F - di * (di - 1.f) - AdF;
      const float c5 = d5F - 2.f * c3f * di - AtF + c3f;
      const float c6p = t1F
                - 3.f * (c3f * c3f)
                + 9.f * t3F
                - 6.f * (di * diag4F)
                + 6.f * diag4F
                - 4.f * c3f
                + 4.f * (di * di * di)
                + 3.f * t8F
                - 12.f * (di * di)
                + 4.f * di;

      float sc3 = c3f, sc4 = c4, sc5 = c5, sc6 = c6p;
      #pragma unroll
      for (int off = 32; off > 0; off >>= 1) {
        sc3 += __shfl_xor(sc3, off);
        sc4 += __shfl_xor(sc4, off);
        sc5 += __shfl_xor(sc5, off);
        sc6 += __shfl_xor(sc6, off);
      }

      const float msk = nmask[b * NN + lane];
      float* xo = out + ((size_t)b * NN + lane) * 3;
      xo[0] = fminf(c3f * 0.5f * msk * 0.1f, 1.f);
      xo[1] = fminf(c4 * 0.5f * msk * 0.1f, 1.f);
      xo[2] = fminf(c5 * 0.5f * msk * 0.1f, 1.f);

      if (lane == 0) {
        float4 y;
        y.x = fminf(sc3 * (1.f / 6.f)  * 0.1f, 1.f);
        y.y = fminf(sc4 * (1.f / 8.f)  * 0.1f, 1.f);
        y.z = fminf(sc5 * (1.f / 10.f) * 0.1f, 1.f);
        y.w = fminf(sc6 * (1.f / 12.f) * 0.1f, 1.f);
        *reinterpret_cast<float4*>(out + (size_t)BATCH * NN * 3 + b * 4) = y;
      }
    }
  }
}

extern "C" void kernel_launch(void* const* d_in, const int* in_sizes, int n_in,
                              void* d_out, int out_size, void* d_ws, size_t ws_size,
                              hipStream_t stream) {
  const float* Ef = reinterpret_cast<const float*>(d_in[0]);
  const float* nmask = reinterpret_cast<const float*>(d_in[1]);
  float* out = reinterpret_cast<float*>(d_out);
  node_cycle_kernel<<<GRID, 256, 0, stream>>>(Ef, nmask, out);
}

// Round 8
// 20.752 us; speedup vs baseline: 1.3547x; 1.2831x over previous
//
#include <hip/hip_runtime.h>

// NodeCycleFeatures via MFMA: B=2048 graphs, N=64, A = E[...,1] symmetric 0/1.
// One wave per batch. k2 = A@A, k3 = k2@A via v_mfma_f32_32x32x16_bf16
// (A is 0/1 bf16-exact; k2<=62 bf16-exact; k3<=3844 f32/u16-exact).
// All matrices are commuting symmetric powers of A -> operand-transpose-immune.
// C/D layout (verified): col=lane&31, row=(reg&3)+8*(reg>>2)+4*(lane>>5).
// k2 stored to LDS COLUMN-major (== row-major by symmetry) -> contiguous b64
// writes; re-read as operand frags row-wise. Per-node sums via LDS row-pass;
// graph sums (t1,t8) reduced in frag space. 16B-block XOR swizzle everywhere.

typedef __attribute__((ext_vector_type(8))) short bf16x8;
typedef __attribute__((ext_vector_type(16))) float f32x16;

constexpr int BATCH = 2048;
constexpr int NN = 64;

__device__ __forceinline__ bf16x8 frag_ld(const unsigned short* buf, int row, int kb2) {
  const int idx = row * 64 + ((kb2 ^ (row & 7)) << 3);  // 16B-block swizzle
  const uint4 v = *reinterpret_cast<const uint4*>(buf + idx);
  union { uint4 u; bf16x8 b; } cv; cv.u = v; return cv.b;
}

__global__ __launch_bounds__(64, 2) void node_cycle_kernel(
    const float4* __restrict__ E4,   // [B,N,N,2] floats viewed as float4
    const float* __restrict__ nmask, // [B,N]
    float* __restrict__ out)         // x: [B,N,3] then y: [B,4]
{
  const int b = blockIdx.x;
  const int lane = threadIdx.x;
  const int h = lane >> 5;          // lane half (also MFMA k-half)
  const int c31 = lane & 31;

  __shared__ unsigned short bufA[64 * 64];  // A bf16; later reused for k3 (u16)
  __shared__ unsigned short bufK2[64 * 64]; // k2 bf16 (col-major == row-major)
  __shared__ float c3sh[NN];
  __shared__ uint2 rms[NN];

  // ---- Phase L: build row masks (coalesced float4 loads + ballot-free or) ----
  const float4* __restrict__ Eb = E4 + (size_t)b * (NN * NN / 2);
  unsigned long long mA = 0ull, mB = 0ull;
  #pragma unroll
  for (int t = 0; t < 32; ++t) {
    const float4 f = Eb[t * 64 + lane];
    const int bit = 2 * t + h;
    mA |= (unsigned long long)(f.y > 0.5f) << bit;
    mB |= (unsigned long long)(f.w > 0.5f) << bit;
  }
  mA |= __shfl_xor(mA, 32);
  mB |= __shfl_xor(mB, 32);
  if (lane < 32) {
    rms[2 * lane]     = make_uint2((unsigned)mA, (unsigned)(mA >> 32));
    rms[2 * lane + 1] = make_uint2((unsigned)mB, (unsigned)(mB >> 32));
  }
  __syncthreads();
  const unsigned mlo = rms[lane].x, mhi = rms[lane].y;   // lane i owns row i

  // ---- Write A as bf16 row-major (swizzled): row=lane, cols from mask ----
  #pragma unroll
  for (int q = 0; q < 8; ++q) {
    unsigned w[4];
    #pragma unroll
    for (int p2 = 0; p2 < 4; ++p2) {
      const int c0 = q * 8 + p2 * 2;
      const unsigned b0 = (c0 < 32 ? (mlo >> c0) : (mhi >> (c0 - 32))) & 1u;
      const unsigned b1 = ((c0 + 1) < 32 ? (mlo >> (c0 + 1)) : (mhi >> (c0 + 1 - 32))) & 1u;
      w[p2] = (b0 ? 0x3F80u : 0u) | (b1 ? 0x3F800000u : 0u);
    }
    const int idx = lane * 64 + ((q ^ (lane & 7)) << 3);
    *reinterpret_cast<uint4*>(&bufA[idx]) = make_uint4(w[0], w[1], w[2], w[3]);
  }
  __syncthreads();

  // ---- A operand frags (A symmetric: same frags serve as A- and B-operand) ----
  bf16x8 Af[2][4];
  #pragma unroll
  for (int R = 0; R < 2; ++R)
    #pragma unroll
    for (int K = 0; K < 4; ++K)
      Af[R][K] = frag_ld(bufA, R * 32 + c31, 2 * K + h);

  // ---- m1: k2 = A @ A ----
  f32x16 a00, a01, a10, a11;
  #pragma unroll
  for (int r = 0; r < 16; ++r) { a00[r] = 0.f; a01[r] = 0.f; a10[r] = 0.f; a11[r] = 0.f; }
  #pragma unroll
  for (int K = 0; K < 4; ++K) {
    a00 = __builtin_amdgcn_mfma_f32_32x32x16_bf16(Af[0][K], Af[0][K], a00, 0, 0, 0);
    a01 = __builtin_amdgcn_mfma_f32_32x32x16_bf16(Af[0][K], Af[1][K], a01, 0, 0, 0);
    a10 = __builtin_amdgcn_mfma_f32_32x32x16_bf16(Af[1][K], Af[0][K], a10, 0, 0, 0);
    a11 = __builtin_amdgcn_mfma_f32_32x32x16_bf16(Af[1][K], Af[1][K], a11, 0, 0, 0);
  }

  // ---- Pack k2 -> bufK2, column-major (== row-major by symmetry), bf16 ----
  // C-frag: col = C*32+c31, row = (r&3)+8*(r>>2)+4*h+32*R. Regs 4g..4g+3 are
  // 4 consecutive rows -> 2 u32 -> one b64 at storage-row col.
  #define PACK_K2(ACC, R, C)                                                    \
  {                                                                             \
    const int c = (C) * 32 + c31;                                               \
    _Pragma("unroll")                                                           \
    for (int g = 0; g < 4; ++g) {                                               \
      const unsigned w0 = (__float_as_uint(ACC[4*g+1]) & 0xffff0000u) |         \
                          (__float_as_uint(ACC[4*g+0]) >> 16);                  \
      const unsigned w1 = (__float_as_uint(ACC[4*g+3]) & 0xffff0000u) |         \
                          (__float_as_uint(ACC[4*g+2]) >> 16);                  \
      const int bb = (4 * (R) + g) ^ (c & 7);                                   \
      *reinterpret_cast<uint2*>(&bufK2[c * 64 + bb * 8 + h * 4]) =              \
          make_uint2(w0, w1);                                                   \
    }                                                                           \
  }
  PACK_K2(a00, 0, 0) PACK_K2(a01, 0, 1) PACK_K2(a10, 1, 0) PACK_K2(a11, 1, 1)
  __syncthreads();

  // ---- k2 operand frags; m2: k3 = k2 @ A ----
  bf16x8 Kf[2][4];
  #pragma unroll
  for (int R = 0; R < 2; ++R)
    #pragma unroll
    for (int K = 0; K < 4; ++K)
      Kf[R][K] = frag_ld(bufK2, R * 32 + c31, 2 * K + h);

  f32x16 d00, d01, d10, d11;
  #pragma unroll
  for (int r = 0; r < 16; ++r) { d00[r] = 0.f; d01[r] = 0.f; d10[r] = 0.f; d11[r] = 0.f; }
  #pragma unroll
  for (int K = 0; K < 4; ++K) {
    d00 = __builtin_amdgcn_mfma_f32_32x32x16_bf16(Kf[0][K], Af[0][K], d00, 0, 0, 0);
    d01 = __builtin_amdgcn_mfma_f32_32x32x16_bf16(Kf[0][K], Af[1][K], d01, 0, 0, 0);
    d10 = __builtin_amdgcn_mfma_f32_32x32x16_bf16(Kf[1][K], Af[0][K], d10, 0, 0, 0);
    d11 = __builtin_amdgcn_mfma_f32_32x32x16_bf16(Kf[1][K], Af[1][K], d11, 0, 0, 0);
  }

  // ---- Frag-space reductions: t1 = sum k3^2, t8 = sum k3, diag(k3) = c3 ----
  float t1p = 0.f, t8p = 0.f;
  #define RED_T18(ACC)                                                          \
  { _Pragma("unroll") for (int r = 0; r < 16; ++r) {                            \
      const float v = ACC[r]; t1p = fmaf(v, v, t1p); t8p += v; } }
  RED_T18(d00) RED_T18(d01) RED_T18(d10) RED_T18(d11)

  const int dtarget = c31 - 4 * h;      // matching reg row-base for diagonal
  float c3d0 = 0.f, c3d1 = 0.f;
  #pragma unroll
  for (int r = 0; r < 16; ++r) {
    const int rowbase = (r & 3) + 8 * (r >> 2);
    c3d0 += (rowbase == dtarget) ? d00[r] : 0.f;   // tile(0,0): node c31
    c3d1 += (rowbase == dtarget) ? d11[r] : 0.f;   // tile(1,1): node 32+c31
  }
  if (((c31 >> 2) & 1) == h) { c3sh[c31] = c3d0; c3sh[32 + c31] = c3d1; }

  // ---- Pack k3 -> bufA (u16 ints; k3 <= 3844 exact) ----
  #define PACK_K3(ACC, R, C)                                                    \
  {                                                                             \
    const int c = (C) * 32 + c31;                                               \
    _Pragma("unroll")                                                           \
    for (int g = 0; g < 4; ++g) {                                               \
      const unsigned u0 = ((unsigned)ACC[4*g+0]) | (((unsigned)ACC[4*g+1]) << 16); \
      const unsigned u1 = ((unsigned)ACC[4*g+2]) | (((unsigned)ACC[4*g+3]) << 16); \
      const int bb = (4 * (R) + g) ^ (c & 7);                                   \
      *reinterpret_cast<uint2*>(&bufA[c * 64 + bb * 8 + h * 4]) =               \
          make_uint2(u0, u1);                                                   \
    }                                                                           \
  }
  PACK_K3(d00, 0, 0) PACK_K3(d01, 0, 1) PACK_K3(d10, 1, 0) PACK_K3(d11, 1, 1)
  __syncthreads();

  // ---- Row-pass: lane i reads row i of k2 (bf16) and k3 (u16) ----
  float diag4 = 0.f, Ad = 0.f, diag5 = 0.f, t3p = 0.f, Atri = 0.f;
  #pragma unroll
  for (int bq = 0; bq < 8; ++bq) {
    const int idx = lane * 64 + ((bq ^ (lane & 7)) << 3);
    const uint4 vk2 = *reinterpret_cast<const uint4*>(&bufK2[idx]);
    const uint4 vk3 = *reinterpret_cast<const uint4*>(&bufA[idx]);
    const float4 c3a = *reinterpret_cast<const float4*>(&c3sh[bq * 8]);     // uniform
    const float4 c3b = *reinterpret_cast<const float4*>(&c3sh[bq * 8 + 4]); // uniform
    const unsigned wk2[4] = {vk2.x, vk2.y, vk2.z, vk2.w};
    const unsigned wk3[4] = {vk3.x, vk3.y, vk3.z, vk3.w};
    const float c3v[8] = {c3a.x, c3a.y, c3a.z, c3a.w, c3b.x, c3b.y, c3b.z, c3b.w};
    #pragma unroll
    for (int e2 = 0; e2 < 4; ++e2) {
      const int j0 = bq * 8 + 2 * e2;
      const float k2lo = __uint_as_float(wk2[e2] << 16);
      const float k2hi = __uint_as_float(wk2[e2] & 0xffff0000u);
      const float k3lo = (float)(wk3[e2] & 0xffffu);
      const float k3hi = (float)(wk3[e2] >> 16);
      diag4 = fmaf(k2lo, k2lo, fmaf(k2hi, k2hi, diag4));
      Ad += k2lo + k2hi;
      diag5 = fmaf(k2lo, k3lo, fmaf(k2hi, k3hi, diag5));
      const unsigned b0 = (j0 < 32 ? (mlo >> j0) : (mhi >> (j0 - 32))) & 1u;
      const unsigned b1 = ((j0 + 1) < 32 ? (mlo >> (j0 + 1)) : (mhi >> (j0 + 1 - 32))) & 1u;
      const float s0 = b0 ? k2lo : 0.f;
      const float s1 = b1 ? k2hi : 0.f;
      t3p = fmaf(s0, k2lo, fmaf(s1, k2hi, t3p));
      Atri += (b0 ? c3v[2 * e2] : 0.f) + (b1 ? c3v[2 * e2 + 1] : 0.f);
    }
  }

  // ---- Per-node quantities ----
  const float di  = (float)(__popc(mlo) + __popc(mhi));
  const float c3i = c3sh[lane];

  const float c4 = diag4 - di * (di - 1.f) - Ad;
  const float c5 = diag5 - 2.f * c3i * di - Atri + c3i;
  const float c6p = t1p + 3.f * t8p           // frag-space partials (any order)
            - 3.f * (c3i * c3i)
            + 9.f * t3p
            - 6.f * (di * diag4)
            + 6.f * diag4
            - 4.f * c3i
            + 4.f * (di * di * di)
            - 12.f * (di * di)
            + 4.f * di;

  // ---- Wave reduction of the four batch sums ----
  float sc3 = c3i, sc4 = c4, sc5 = c5, sc6 = c6p;
  #pragma unroll
  for (int off = 32; off > 0; off >>= 1) {
    sc3 += __shfl_xor(sc3, off);
    sc4 += __shfl_xor(sc4, off);
    sc5 += __shfl_xor(sc5, off);
    sc6 += __shfl_xor(sc6, off);
  }

  // ---- Outputs ----
  const float m = nmask[b * NN + lane];
  float* xo = out + ((size_t)b * NN + lane) * 3;
  xo[0] = fminf(c3i * 0.5f * m * 0.1f, 1.f);
  xo[1] = fminf(c4 * 0.5f * m * 0.1f, 1.f);
  xo[2] = fminf(c5 * 0.5f * m * 0.1f, 1.f);

  if (lane == 0) {
    float4 y;
    y.x = fminf(sc3 * (1.f / 6.f)  * 0.1f, 1.f);
    y.y = fminf(sc4 * (1.f / 8.f)  * 0.1f, 1.f);
    y.z = fminf(sc5 * (1.f / 10.f) * 0.1f, 1.f);
    y.w = fminf(sc6 * (1.f / 12.f) * 0.1f, 1.f);
    *reinterpret_cast<float4*>(out + (size_t)BATCH * NN * 3 + b * 4) = y;
  }
}

extern "C" void kernel_launch(void* const* d_in, const int* in_sizes, int n_in,
                              void* d_out, int out_size, void* d_ws, size_t ws_size,
                              hipStream_t stream) {
  const float4* E4 = reinterpret_cast<const float4*>(d_in[0]);
  const float* nmask = reinterpret_cast<const float*>(d_in[1]);
  float* out = reinterpret_cast<float*>(d_out);
  node_cycle_kernel<<<BATCH, NN, 0, stream>>>(E4, nmask, out);
}

// Round 9
// 19.304 us; speedup vs baseline: 1.4562x; 1.0750x over previous
//
#include <hip/hip_runtime.h>

// NodeCycleFeatures via MFMA, 4 waves/batch: B=2048, N=64, A symmetric 0/1.
// 256-thread block per batch; wave w owns MFMA tile (R,C) = (w>>1, w&1) of
// k2 = A@A and k3 = k2@A (v_mfma_f32_32x32x16_bf16; all values integer-exact).
// C/D layout (verified R8): col=lane&31, row=(reg&3)+8*(reg>>2)+4*(lane>>5).
// k2/k3 stored col-major (== row-major by symmetry) with 16B-block XOR swizzle.
// Wave w also does column-quarter w of the per-row reduction pass.

typedef __attribute__((ext_vector_type(8))) short bf16x8;
typedef __attribute__((ext_vector_type(16))) float f32x16;

constexpr int BATCH = 2048;
constexpr int NN = 64;

__device__ __forceinline__ bf16x8 frag_ld(const unsigned short* buf, int row, int kb2) {
  const int idx = row * 64 + ((kb2 ^ (row & 7)) << 3);  // 16B-block swizzle
  const uint4 v = *reinterpret_cast<const uint4*>(buf + idx);
  union { uint4 u; bf16x8 b; } cv; cv.u = v; return cv.b;
}

__global__ __launch_bounds__(256, 5) void node_cycle_kernel(
    const float4* __restrict__ E4,   // [B,N,N,2] floats viewed as float4
    const float* __restrict__ nmask, // [B,N]
    float* __restrict__ out)         // x: [B,N,3] then y: [B,4]
{
  const int b = blockIdx.x;
  const int tid = threadIdx.x;
  const int lane = tid & 63;
  const int w = tid >> 6;            // wave id 0..3
  const int h = lane >> 5;           // lane half (MFMA k-half)
  const int c31 = lane & 31;
  const int R = w >> 1, C = w & 1;   // this wave's tile

  __shared__ unsigned short bufA[64 * 64];   // A bf16; reused for k3 (u16)
  __shared__ unsigned short bufK2[64 * 64];  // k2 bf16 (col-major == row-major)
  __shared__ unsigned short sl[4][64];       // per-wave 16-bit col-mask slices
  __shared__ uint2 rms[NN];                  // full row masks
  __shared__ float c3sh[NN];
  __shared__ float accs[4][7][NN];           // per-quarter row partials

  const float4* __restrict__ Eb = E4 + (size_t)b * (NN * NN / 2);

  // ---- Phase L: wave w loads rows [16w,16w+16) (coalesced), builds 16-bit
  // column-mask slices. float4 i=w*512+q*64+lane: row=16w+2q+h, colpair=lane&31.
  unsigned mA = 0u, mB = 0u;
  #pragma unroll
  for (int q = 0; q < 8; ++q) {
    const float4 f = Eb[w * 512 + q * 64 + lane];
    const int bit = 2 * q + h;
    mA |= (unsigned)(f.y > 0.5f) << bit;   // col 2*(lane&31)
    mB |= (unsigned)(f.w > 0.5f) << bit;   // col 2*(lane&31)+1
  }
  mA |= (unsigned)__shfl_xor((int)mA, 32);
  mB |= (unsigned)__shfl_xor((int)mB, 32);
  if (lane < 32) {
    sl[w][2 * lane]     = (unsigned short)mA;
    sl[w][2 * lane + 1] = (unsigned short)mB;
  }
  __syncthreads();                                    // B1

  // ---- Assemble full row masks (col mask == row mask; A symmetric) ----
  if (tid < 128) {
    const int c = tid >> 1, hf = tid & 1;
    const unsigned v = (unsigned)sl[2 * hf][c] | ((unsigned)sl[2 * hf + 1][c] << 16);
    if (hf == 0) rms[c].x = v; else rms[c].y = v;
  }
  __syncthreads();                                    // B2

  const uint2 mr = rms[lane];                         // row `lane` mask

  // ---- Write A as bf16 (swizzled row-major): row=lane, col-quarter w ----
  {
    const unsigned word = (w < 2) ? mr.x : mr.y;
    const unsigned bits16 = (word >> (16 * (w & 1))) & 0xffffu;
    #pragma unroll
    for (int e = 0; e < 2; ++e) {
      const int bq = 2 * w + e;
      unsigned wv[4];
      #pragma unroll
      for (int p2 = 0; p2 < 4; ++p2) {
        const int c0 = e * 8 + p2 * 2;
        const unsigned b0 = (bits16 >> c0) & 1u;
        const unsigned b1 = (bits16 >> (c0 + 1)) & 1u;
        wv[p2] = (b0 ? 0x3F80u : 0u) | (b1 ? 0x3F800000u : 0u);
      }
      const int idx = lane * 64 + ((bq ^ (lane & 7)) << 3);
      *reinterpret_cast<uint4*>(&bufA[idx]) = make_uint4(wv[0], wv[1], wv[2], wv[3]);
    }
  }
  __syncthreads();                                    // B3

  // ---- Frags + m1: k2 tile (R,C) = A[R-block] @ A[C-block] ----
  bf16x8 Af[4], Bf[4];
  #pragma unroll
  for (int K = 0; K < 4; ++K) {
    Af[K] = frag_ld(bufA, R * 32 + c31, 2 * K + h);
    Bf[K] = frag_ld(bufA, C * 32 + c31, 2 * K + h);
  }
  f32x16 acc;
  #pragma unroll
  for (int r = 0; r < 16; ++r) acc[r] = 0.f;
  #pragma unroll
  for (int K = 0; K < 4; ++K)
    acc = __builtin_amdgcn_mfma_f32_32x32x16_bf16(Af[K], Bf[K], acc, 0, 0, 0);

  // ---- Pack k2 tile -> bufK2 col-major bf16 (regs 4g..4g+3 = 4 rows) ----
  {
    const int c = C * 32 + c31;
    #pragma unroll
    for (int g = 0; g < 4; ++g) {
      const unsigned w0 = (__float_as_uint(acc[4*g+1]) & 0xffff0000u) |
                          (__float_as_uint(acc[4*g+0]) >> 16);
      const unsigned w1 = (__float_as_uint(acc[4*g+3]) & 0xffff0000u) |
                          (__float_as_uint(acc[4*g+2]) >> 16);
      const int bb = (4 * R + g) ^ (c & 7);
      *reinterpret_cast<uint2*>(&bufK2[c * 64 + bb * 8 + h * 4]) = make_uint2(w0, w1);
    }
  }
  __syncthreads();                                    // B4

  // ---- m2: k3 tile (R,C) = k2[R-block] @ A[C-block] ----
  bf16x8 Kf[4];
  #pragma unroll
  for (int K = 0; K < 4; ++K)
    Kf[K] = frag_ld(bufK2, R * 32 + c31, 2 * K + h);
  f32x16 d;
  #pragma unroll
  for (int r = 0; r < 16; ++r) d[r] = 0.f;
  #pragma unroll
  for (int K = 0; K < 4; ++K)
    d = __builtin_amdgcn_mfma_f32_32x32x16_bf16(Kf[K], Bf[K], d, 0, 0, 0);

  // ---- c3 = diag(k3): diagonal tiles only ----
  if (R == C) {
    const int dtarget = c31 - 4 * h;
    float c3d = 0.f;
    #pragma unroll
    for (int r = 0; r < 16; ++r) {
      const int rowbase = (r & 3) + 8 * (r >> 2);
      c3d += (rowbase == dtarget) ? d[r] : 0.f;
    }
    if (((c31 >> 2) & 1) == h) c3sh[R * 32 + c31] = c3d;
  }

  // ---- Pack k3 tile -> bufA as u16 (k3 <= 3844 exact; A no longer needed) ----
  {
    const int c = C * 32 + c31;
    #pragma unroll
    for (int g = 0; g < 4; ++g) {
      const unsigned u0 = ((unsigned)d[4*g+0]) | (((unsigned)d[4*g+1]) << 16);
      const unsigned u1 = ((unsigned)d[4*g+2]) | (((unsigned)d[4*g+3]) << 16);
      const int bb = (4 * R + g) ^ (c & 7);
      *reinterpret_cast<uint2*>(&bufA[c * 64 + bb * 8 + h * 4]) = make_uint2(u0, u1);
    }
  }
  __syncthreads();                                    // B5

  // ---- Row-pass: row = lane, column-quarter = w (16 cols / thread) ----
  float diag4 = 0.f, Ad = 0.f, diag5 = 0.f, t3p = 0.f, Atri = 0.f;
  float t1p = 0.f, t8p = 0.f;
  #pragma unroll
  for (int e = 0; e < 2; ++e) {
    const int bq = 2 * w + e;
    const int idx = lane * 64 + ((bq ^ (lane & 7)) << 3);
    const uint4 vk2 = *reinterpret_cast<const uint4*>(&bufK2[idx]);
    const uint4 vk3 = *reinterpret_cast<const uint4*>(&bufA[idx]);
    const float4 c3a = *reinterpret_cast<const float4*>(&c3sh[bq * 8]);     // uniform
    const float4 c3b = *reinterpret_cast<const float4*>(&c3sh[bq * 8 + 4]); // uniform
    const unsigned wk2[4] = {vk2.x, vk2.y, vk2.z, vk2.w};
    const unsigned wk3[4] = {vk3.x, vk3.y, vk3.z, vk3.w};
    const float c3v[8] = {c3a.x, c3a.y, c3a.z, c3a.w, c3b.x, c3b.y, c3b.z, c3b.w};
    #pragma unroll
    for (int e2 = 0; e2 < 4; ++e2) {
      const int j0 = bq * 8 + 2 * e2;
      const float k2lo = __uint_as_float(wk2[e2] << 16);
      const float k2hi = __uint_as_float(wk2[e2] & 0xffff0000u);
      const float k3lo = (float)(wk3[e2] & 0xffffu);
      const float k3hi = (float)(wk3[e2] >> 16);
      diag4 = fmaf(k2lo, k2lo, fmaf(k2hi, k2hi, diag4));
      Ad += k2lo + k2hi;                         // (A@d)[r] = row-sum of k2
      diag5 = fmaf(k2lo, k3lo, fmaf(k2hi, k3hi, diag5));
      t1p = fmaf(k3lo, k3lo, fmaf(k3hi, k3hi, t1p));   // -> trace(k6)
      t8p += k3lo + k3hi;                               // -> sum(k3)
      const unsigned b0 = (j0 < 32 ? (mr.x >> j0) : (mr.y >> (j0 - 32))) & 1u;
      const unsigned b1 = ((j0 + 1) < 32 ? (mr.x >> (j0 + 1)) : (mr.y >> (j0 + 1 - 32))) & 1u;
      const float s0 = b0 ? k2lo : 0.f;
      const float s1 = b1 ? k2hi : 0.f;
      t3p = fmaf(s0, k2lo, fmaf(s1, k2hi, t3p));
      Atri += (b0 ? c3v[2 * e2] : 0.f) + (b1 ? c3v[2 * e2 + 1] : 0.f);
    }
  }
  accs[w][0][lane] = diag4;
  accs[w][1][lane] = Ad;
  accs[w][2][lane] = diag5;
  accs[w][3][lane] = t3p;
  accs[w][4][lane] = Atri;
  accs[w][5][lane] = t1p;
  accs[w][6][lane] = t8p;
  __syncthreads();                                    // B6

  // ---- Final: wave 0 merges quarters, computes node/graph outputs ----
  if (w == 0) {
    float f[7];
    #pragma unroll
    for (int q2 = 0; q2 < 7; ++q2)
      f[q2] = accs[0][q2][lane] + accs[1][q2][lane]
            + accs[2][q2][lane] + accs[3][q2][lane];
    const float diag4F = f[0], AdF = f[1], d5F = f[2], t3F = f[3],
                AtF = f[4], t1F = f[5], t8F = f[6];
    const float di  = (float)(__popc(mr.x) + __popc(mr.y));
    const float c3i = c3sh[lane];

    const float c4 = diag4F - di * (di - 1.f) - AdF;
    const float c5 = d5F - 2.f * c3i * di - AtF + c3i;
    const float c6p = t1F + 3.f * t8F        // per-row partials (wave-sum = total)
              - 3.f * (c3i * c3i)
              + 9.f * t3F
              - 6.f * (di * diag4F)
              + 6.f * diag4F
              - 4.f * c3i
              + 4.f * (di * di * di)
              - 12.f * (di * di)
              + 4.f * di;

    float sc3 = c3i, sc4 = c4, sc5 = c5, sc6 = c6p;
    #pragma unroll
    for (int off = 32; off > 0; off >>= 1) {
      sc3 += __shfl_xor(sc3, off);
      sc4 += __shfl_xor(sc4, off);
      sc5 += __shfl_xor(sc5, off);
      sc6 += __shfl_xor(sc6, off);
    }

    const float m = nmask[b * NN + lane];
    float* xo = out + ((size_t)b * NN + lane) * 3;
    xo[0] = fminf(c3i * 0.5f * m * 0.1f, 1.f);
    xo[1] = fminf(c4 * 0.5f * m * 0.1f, 1.f);
    xo[2] = fminf(c5 * 0.5f * m * 0.1f, 1.f);

    if (lane == 0) {
      float4 y;
      y.x = fminf(sc3 * (1.f / 6.f)  * 0.1f, 1.f);
      y.y = fminf(sc4 * (1.f / 8.f)  * 0.1f, 1.f);
      y.z = fminf(sc5 * (1.f / 10.f) * 0.1f, 1.f);
      y.w = fminf(sc6 * (1.f / 12.f) * 0.1f, 1.f);
      *reinterpret_cast<float4*>(out + (size_t)BATCH * NN * 3 + b * 4) = y;
    }
  }
}

extern "C" void kernel_launch(void* const* d_in, const int* in_sizes, int n_in,
                              void* d_out, int out_size, void* d_ws, size_t ws_size,
                              hipStream_t stream) {
  const float4* E4 = reinterpret_cast<const float4*>(d_in[0]);
  const float* nmask = reinterpret_cast<const float*>(d_in[1]);
  float* out = reinterpret_cast<float*>(d_out);
  node_cycle_kernel<<<BATCH, 256, 0, stream>>>(E4, nmask, out);
}

// Round 10
// 18.845 us; speedup vs baseline: 1.4918x; 1.0244x over previous
//
#include <hip/hip_runtime.h>

// NodeCycleFeatures via MFMA, 4 waves/batch, full-occupancy variant.
// B=2048, N=64, A = E[...,1] symmetric 0/1, zero diag.
// Wave w owns MFMA tile (R,C)=(w>>1,w&1) of k2=A@A and k3=k2@A
// (v_mfma_f32_32x32x16_bf16; all values integer-exact in bf16/u16/f32).
// C/D layout (verified R8/R9): col=lane&31, row=(reg&3)+8*(reg>>2)+4*(lane>>5).
// k2/k3 stored col-major (== row-major by symmetry), 16B-block XOR swizzle.
// Row-pass: wave w owns ROWS [16w,16w+16), 4 lanes/row; partials merged by
// 2-level shfl butterfly (no accs LDS). LDS ~17.7KB -> 8 blocks/CU resident.

typedef __attribute__((ext_vector_type(8))) short bf16x8;
typedef __attribute__((ext_vector_type(16))) float f32x16;

constexpr int BATCH = 2048;
constexpr int NN = 64;

__device__ __forceinline__ bf16x8 frag_ld(const unsigned short* buf, int row, int kb2) {
  const int idx = row * 64 + ((kb2 ^ (row & 7)) << 3);  // 16B-block swizzle
  const uint4 v = *reinterpret_cast<const uint4*>(buf + idx);
  union { uint4 u; bf16x8 b; } cv; cv.u = v; return cv.b;
}

__global__ __launch_bounds__(256, 8) void node_cycle_kernel(
    const float4* __restrict__ E4,   // [B,N,N,2] floats viewed as float4
    const float* __restrict__ nmask, // [B,N]
    float* __restrict__ out)         // x: [B,N,3] then y: [B,4]
{
  const int b = blockIdx.x;
  const int tid = threadIdx.x;
  const int lane = tid & 63;
  const int w = tid >> 6;            // wave id 0..3
  const int h = lane >> 5;           // lane half (MFMA k-half)
  const int c31 = lane & 31;
  const int R = w >> 1, C = w & 1;   // this wave's MFMA tile

  __shared__ unsigned short bufA[64 * 64];   // A bf16; reused for k3 (u16)
  __shared__ unsigned short bufK2[64 * 64];  // k2 bf16 (col-major == row-major)
  __shared__ unsigned short sl[4][64];       // per-wave 16-bit col-mask slices
  __shared__ uint2 rms[NN];                  // full row masks
  __shared__ float c3sh[NN];
  __shared__ float4 gpart[4];                // per-wave graph-sum partials

  const float4* __restrict__ Eb = E4 + (size_t)b * (NN * NN / 2);

  // Row-pass ownership: wave w rows [16w,16w+16), 4 lanes per row.
  const int rp_r = 16 * w + (lane >> 2);
  const int rp_q = lane & 3;
  const float m_r = nmask[b * NN + rp_r];    // early scalar global load

  // ---- Phase L: wave w loads rows [16w,16w+16) (coalesced float4), builds
  // 16-bit column-mask slices. float4 i=w*512+q*64+lane: row=16w+2q+h,
  // colpair=lane&31 (.y=col 2c, .w=col 2c+1).
  unsigned mA = 0u, mB = 0u;
  #pragma unroll
  for (int q = 0; q < 8; ++q) {
    const float4 f = Eb[w * 512 + q * 64 + lane];
    const int bit = 2 * q + h;
    mA |= (unsigned)(f.y > 0.5f) << bit;
    mB |= (unsigned)(f.w > 0.5f) << bit;
  }
  mA |= (unsigned)__shfl_xor((int)mA, 32);
  mB |= (unsigned)__shfl_xor((int)mB, 32);
  if (lane < 32) {
    sl[w][2 * lane]     = (unsigned short)mA;
    sl[w][2 * lane + 1] = (unsigned short)mB;
  }
  __syncthreads();                                    // B1

  // ---- Assemble full row masks (col mask == row mask; A symmetric) ----
  if (tid < 128) {
    const int c = tid >> 1, hf = tid & 1;
    const unsigned v = (unsigned)sl[2 * hf][c] | ((unsigned)sl[2 * hf + 1][c] << 16);
    if (hf == 0) rms[c].x = v; else rms[c].y = v;
  }
  __syncthreads();                                    // B2

  const uint2 mrL = rms[lane];

  // ---- Write A as bf16 (swizzled row-major): row=lane, col-quarter w ----
  {
    const unsigned word = (w < 2) ? mrL.x : mrL.y;
    const unsigned bits16 = (word >> (16 * (w & 1))) & 0xffffu;
    #pragma unroll
    for (int e = 0; e < 2; ++e) {
      const int bq = 2 * w + e;
      unsigned wv[4];
      #pragma unroll
      for (int p2 = 0; p2 < 4; ++p2) {
        const int c0 = e * 8 + p2 * 2;
        wv[p2] = (((bits16 >> c0) & 1u) ? 0x3F80u : 0u)
               | (((bits16 >> (c0 + 1)) & 1u) ? 0x3F800000u : 0u);
      }
      const int idx = lane * 64 + ((bq ^ (lane & 7)) << 3);
      *reinterpret_cast<uint4*>(&bufA[idx]) = make_uint4(wv[0], wv[1], wv[2], wv[3]);
    }
  }
  __syncthreads();                                    // B3

  // ---- m1: k2 tile (R,C). Bf hoisted (reused by m2); Af staged per-K ----
  bf16x8 Bf[4];
  #pragma unroll
  for (int K = 0; K < 4; ++K) Bf[K] = frag_ld(bufA, C * 32 + c31, 2 * K + h);

  f32x16 acc;
  #pragma unroll
  for (int r = 0; r < 16; ++r) acc[r] = 0.f;
  #pragma unroll
  for (int K = 0; K < 4; ++K) {
    const bf16x8 af = frag_ld(bufA, R * 32 + c31, 2 * K + h);
    acc = __builtin_amdgcn_mfma_f32_32x32x16_bf16(af, Bf[K], acc, 0, 0, 0);
  }

  // ---- Pack k2 tile -> bufK2 col-major bf16 (regs 4g..4g+3 = 4 rows) ----
  {
    const int c = C * 32 + c31;
    #pragma unroll
    for (int g = 0; g < 4; ++g) {
      const unsigned w0 = (__float_as_uint(acc[4*g+1]) & 0xffff0000u) |
                          (__float_as_uint(acc[4*g+0]) >> 16);
      const unsigned w1 = (__float_as_uint(acc[4*g+3]) & 0xffff0000u) |
                          (__float_as_uint(acc[4*g+2]) >> 16);
      const int bb = (4 * R + g) ^ (c & 7);
      *reinterpret_cast<uint2*>(&bufK2[c * 64 + bb * 8 + h * 4]) = make_uint2(w0, w1);
    }
  }
  __syncthreads();                                    // B4

  // ---- m2: k3 tile (R,C) = k2[R] @ A[C] (Kf staged per-K, Bf in regs) ----
  f32x16 d;
  #pragma unroll
  for (int r = 0; r < 16; ++r) d[r] = 0.f;
  #pragma unroll
  for (int K = 0; K < 4; ++K) {
    const bf16x8 kf = frag_ld(bufK2, R * 32 + c31, 2 * K + h);
    d = __builtin_amdgcn_mfma_f32_32x32x16_bf16(kf, Bf[K], d, 0, 0, 0);
  }

  // ---- c3 = diag(k3): diagonal tiles only ----
  if (R == C) {
    const int dtarget = c31 - 4 * h;
    float c3d = 0.f;
    #pragma unroll
    for (int r = 0; r < 16; ++r) {
      const int rowbase = (r & 3) + 8 * (r >> 2);
      c3d += (rowbase == dtarget) ? d[r] : 0.f;
    }
    if (((c31 >> 2) & 1) == h) c3sh[R * 32 + c31] = c3d;
  }

  // ---- Pack k3 tile -> bufA as u16 (k3 <= 3844 exact; all bufA reads done) ----
  {
    const int c = C * 32 + c31;
    #pragma unroll
    for (int g = 0; g < 4; ++g) {
      const unsigned u0 = ((unsigned)d[4*g+0]) | (((unsigned)d[4*g+1]) << 16);
      const unsigned u1 = ((unsigned)d[4*g+2]) | (((unsigned)d[4*g+3]) << 16);
      const int bb = (4 * R + g) ^ (c & 7);
      *reinterpret_cast<uint2*>(&bufA[c * 64 + bb * 8 + h * 4]) = make_uint2(u0, u1);
    }
  }
  __syncthreads();                                    // B5

  // ---- Row-pass: lane -> (row rp_r, col-quarter rp_q), 16 cols/lane ----
  const uint2 mr = rms[rp_r];                         // 4-lane broadcast
  float diag4 = 0.f, Ad = 0.f, diag5 = 0.f, t3p = 0.f, Atri = 0.f;
  float t1p = 0.f, t8p = 0.f;
  #pragma unroll
  for (int e = 0; e < 2; ++e) {
    const int bq = 2 * rp_q + e;
    const int idx = rp_r * 64 + ((bq ^ (rp_r & 7)) << 3);
    const uint4 vk2 = *reinterpret_cast<const uint4*>(&bufK2[idx]);
    const uint4 vk3 = *reinterpret_cast<const uint4*>(&bufA[idx]);
    const float4 c3a = *reinterpret_cast<const float4*>(&c3sh[bq * 8]);
    const float4 c3b = *reinterpret_cast<const float4*>(&c3sh[bq * 8 + 4]);
    const unsigned wk2[4] = {vk2.x, vk2.y, vk2.z, vk2.w};
    const unsigned wk3[4] = {vk3.x, vk3.y, vk3.z, vk3.w};
    const float c3v[8] = {c3a.x, c3a.y, c3a.z, c3a.w, c3b.x, c3b.y, c3b.z, c3b.w};
    #pragma unroll
    for (int e2 = 0; e2 < 4; ++e2) {
      const int j0 = bq * 8 + 2 * e2;
      const float k2lo = __uint_as_float(wk2[e2] << 16);
      const float k2hi = __uint_as_float(wk2[e2] & 0xffff0000u);
      const float k3lo = (float)(wk3[e2] & 0xffffu);
      const float k3hi = (float)(wk3[e2] >> 16);
      diag4 = fmaf(k2lo, k2lo, fmaf(k2hi, k2hi, diag4));
      Ad += k2lo + k2hi;                              // (A@d)[r] = row-sum of k2
      diag5 = fmaf(k2lo, k3lo, fmaf(k2hi, k3hi, diag5));
      t1p = fmaf(k3lo, k3lo, fmaf(k3hi, k3hi, t1p));  // -> trace(k6)
      t8p += k3lo + k3hi;                             // -> sum(k3)
      const unsigned b0 = (j0 < 32 ? (mr.x >> j0) : (mr.y >> (j0 - 32))) & 1u;
      const unsigned b1 = ((j0 + 1) < 32 ? (mr.x >> (j0 + 1)) : (mr.y >> (j0 + 1 - 32))) & 1u;
      t3p = fmaf(b0 ? k2lo : 0.f, k2lo, fmaf(b1 ? k2hi : 0.f, k2hi, t3p));
      Atri += (b0 ? c3v[2 * e2] : 0.f) + (b1 ? c3v[2 * e2 + 1] : 0.f);
    }
  }
  // 2-level butterfly over the 4 quarter-lanes of each row
  #pragma unroll
  for (int off = 1; off <= 2; off <<= 1) {
    diag4 += __shfl_xor(diag4, off);
    Ad    += __shfl_xor(Ad, off);
    diag5 += __shfl_xor(diag5, off);
    t3p   += __shfl_xor(t3p, off);
    Atri  += __shfl_xor(Atri, off);
    t1p   += __shfl_xor(t1p, off);
    t8p   += __shfl_xor(t8p, off);
  }

  // ---- Per-row quantities (all 4 lanes of a row hold full-row values) ----
  const float di  = (float)(__popc(mr.x) + __popc(mr.y));
  const float c3i = c3sh[rp_r];
  const float c4 = diag4 - di * (di - 1.f) - Ad;
  const float c5 = diag5 - 2.f * c3i * di - Atri + c3i;
  const float c6p = t1p + 3.f * t8p
            - 3.f * (c3i * c3i)
            + 9.f * t3p
            - 6.f * (di * diag4)
            + 6.f * diag4
            - 4.f * c3i
            + 4.f * (di * di * di)
            - 12.f * (di * di)
            + 4.f * di;

  // ---- x outputs: one lane per row ----
  if (rp_q == 0) {
    float* xo = out + ((size_t)b * NN + rp_r) * 3;
    xo[0] = fminf(c3i * 0.05f * m_r, 1.f);
    xo[1] = fminf(c4  * 0.05f * m_r, 1.f);
    xo[2] = fminf(c5  * 0.05f * m_r, 1.f);
  }

  // ---- Graph sums: lanes l, l+4, ..., l+60 are 16 distinct rows ----
  float sc3 = c3i, sc4 = c4, sc5 = c5, sc6 = c6p;
  #pragma unroll
  for (int off = 4; off < 64; off <<= 1) {
    sc3 += __shfl_xor(sc3, off);
    sc4 += __shfl_xor(sc4, off);
    sc5 += __shfl_xor(sc5, off);
    sc6 += __shfl_xor(sc6, off);
  }
  if (lane == 0) gpart[w] = make_float4(sc3, sc4, sc5, sc6);
  __syncthreads();                                    // B6

  if (tid == 0) {
    const float4 g0 = gpart[0], g1 = gpart[1], g2 = gpart[2], g3 = gpart[3];
    float4 y;
    y.x = fminf((g0.x + g1.x + g2.x + g3.x) * (1.f / 6.f)  * 0.1f, 1.f);
    y.y = fminf((g0.y + g1.y + g2.y + g3.y) * (1.f / 8.f)  * 0.1f, 1.f);
    y.z = fminf((g0.z + g1.z + g2.z + g3.z) * (1.f / 10.f) * 0.1f, 1.f);
    y.w = fminf((g0.w + g1.w + g2.w + g3.w) * (1.f / 12.f) * 0.1f, 1.f);
    *reinterpret_cast<float4*>(out + (size_t)BATCH * NN * 3 + b * 4) = y;
  }
}

extern "C" void kernel_launch(void* const* d_in, const int* in_sizes, int n_in,
                              void* d_out, int out_size, void* d_ws, size_t ws_size,
                              hipStream_t stream) {
  const float4* E4 = reinterpret_cast<const float4*>(d_in[0]);
  const float* nmask = reinterpret_cast<const float*>(d_in[1]);
  float* out = reinterpret_cast<float*>(d_out);
  node_cycle_kernel<<<BATCH, 256, 0, stream>>>(E4, nmask, out);
}